// Round 8
// baseline (150.926 us; speedup 1.0000x reference)
//
#include <hip/hip_runtime.h>
#include <hip/hip_bf16.h>

#define NPTS   131072
#define NNODES 2048
#define KSEL   32

// ---- knn decomposition ----
#define TKNN   256                 // threads per knn block
#define PPT    2                   // points per thread = 1 packed f32x2 chain
#define PPG_K  (TKNN * PPT)        // 512 points per knn group
#define NGRP_K (NPTS / PPG_K)      // 256 knn groups
#define NCHUNK 8                   // node chunks; partial-array merge (no atomics)
#define CHN    (NNODES / NCHUNK)   // 256 nodes per chunk
#define HALF   (CHN / 2)           // 128: dual-accumulator split point
// grid = 256*8 = 2048 blocks

// ---- grouping/scatter decomposition ----
#define GSZ    512                 // points per stability group
#define NG     (NPTS / GSZ)        // 256 groups

typedef unsigned int uint;
typedef unsigned short u16;
typedef unsigned long long u64;
typedef float f2 __attribute__((ext_vector_type(2)));

__device__ __forceinline__ f2 splat(float s) { return (f2){s, s}; }

// order-preserving fp32 -> u32 (handles tiny-negative cancellation results)
__device__ __forceinline__ uint f2ord(float d) {
    uint b = __float_as_uint(d);
    return (b & 0x80000000u) ? ~b : (b | 0x80000000u);
}
__device__ __forceinline__ float ord2f(uint t) {
    uint b = (t & 0x80000000u) ? (t ^ 0x80000000u) : ~t;
    return __uint_as_float(b);
}

// exact distance sequence (pinned rounding): m=nx*x; r=fma(ny,y,m);
// r=fma(nz,z,r); d=(pp+r)+nn  -- lane-wise IEEE f32, bit-identical to the
// accepted reference-matching sequence (VGPR vs SGPR operands do not change
// the arithmetic).
__device__ __forceinline__ f2 dist2(const f2& nx2, const f2& ny2, const f2& nz2,
                                    const f2& pp2, float4 v) {
    f2 m = nx2 * splat(v.x);                               // v_pk_mul_f32
    f2 r = __builtin_elementwise_fma(ny2, splat(v.y), m);  // v_pk_fma_f32
    r    = __builtin_elementwise_fma(nz2, splat(v.z), r);  // v_pk_fma_f32
    return (pp2 + r) + splat(v.w);                         // 2x v_pk_add_f32
}

// --- K0: pack nodes {x,y,z,|n|^2} (8 blocks) --- [proven R1/R7]
__global__ __launch_bounds__(256) void prep_nodes(const float* __restrict__ nodes,
                                                  float4* __restrict__ n4) {
    int i = blockIdx.x * 256 + threadIdx.x;
    float x = nodes[3 * i], y = nodes[3 * i + 1], z = nodes[3 * i + 2];
    // |n|^2 with numpy's mul-then-add rounding
    float nn = __fadd_rn(__fadd_rn(__fmul_rn(x, x), __fmul_rn(y, y)), __fmul_rn(z, z));
    n4[i] = make_float4(x, y, z, nn);
}

// load one dual-half 4-node batch (8 float4) into VGPR buffers.
// npv is divergence-tainted -> global_load_dwordx4 (vmcnt-tracked), not s_load.
__device__ __forceinline__ void loadb(const float4* npv, int j,
                                      float4* __restrict__ A,
                                      float4* __restrict__ B) {
    #pragma unroll
    for (int o = 0; o < 4; ++o) {
        A[o] = npv[j + o];
        B[o] = npv[HALF + j + o];
    }
}

// one 4-node dual-half argmin step at base jj (logic byte-identical to R7)
__device__ __forceinline__ void step4(const float4* __restrict__ A,
                                      const float4* __restrict__ B, int jj,
                                      const f2& nx2, const f2& ny2, const f2& nz2,
                                      const f2& pp2,
                                      float* __restrict__ bestA, int* __restrict__ qbA,
                                      float* __restrict__ bestB, int* __restrict__ qbB) {
    f2 dA0 = dist2(nx2, ny2, nz2, pp2, A[0]);
    f2 dA1 = dist2(nx2, ny2, nz2, pp2, A[1]);
    f2 dA2 = dist2(nx2, ny2, nz2, pp2, A[2]);
    f2 dA3 = dist2(nx2, ny2, nz2, pp2, A[3]);
    f2 dB0 = dist2(nx2, ny2, nz2, pp2, B[0]);
    f2 dB1 = dist2(nx2, ny2, nz2, pp2, B[1]);
    f2 dB2 = dist2(nx2, ny2, nz2, pp2, B[2]);
    f2 dB3 = dist2(nx2, ny2, nz2, pp2, B[3]);

    #pragma unroll
    for (int p = 0; p < PPT; ++p) {
        float eA0 = p ? dA0.y : dA0.x;
        float eA1 = p ? dA1.y : dA1.x;
        float eA2 = p ? dA2.y : dA2.x;
        float eA3 = p ? dA3.y : dA3.x;
        float mA  = fminf(fminf(bestA[p], eA0), eA1);   // v_min3_f32
        float nA  = fminf(fminf(mA, eA2), eA3);         // v_min3_f32
        qbA[p]    = (nA < bestA[p]) ? jj : qbA[p];      // strict: first quad wins
        bestA[p]  = nA;

        float eB0 = p ? dB0.y : dB0.x;
        float eB1 = p ? dB1.y : dB1.x;
        float eB2 = p ? dB2.y : dB2.x;
        float eB3 = p ? dB3.y : dB3.x;
        float mB  = fminf(fminf(bestB[p], eB0), eB1);
        float nB  = fminf(fminf(mB, eB2), eB3);
        qbB[p]    = (nB < bestB[p]) ? jj : qbB[p];      // relative to HALF
        bestB[p]  = nB;
    }
}

// --- K1: partial 1-NN, 2 pts/thread as 1 packed-f32 chain (v_pk_* VOP3P) ---
// [argmin logic proven R3/R7; store path proven R4/R7]
// NEW: node batches in VGPR double-buffers, software-pipelined: issue batch
// k+1's global loads before computing batch k, so the once-touched (K$/L1-cold)
// node reads overlap ~190cy of compute per wave -- independent of wave phasing.
// Dual-half quad-deferred argmin; strict-improvement base keeps first
// occurrence; tie across halves -> A (lower indices); endgame recomputes the
// winning quad bit-identically and takes the first exact match.
__global__ __launch_bounds__(256) void knn_part(const float* __restrict__ pts,
                                                const float4* __restrict__ n4,
                                                u64* __restrict__ part) {
    int bid = blockIdx.x;
    int c   = bid & (NCHUNK - 1);            // block-uniform chunk
    int g   = bid >> 3;                      // knn point group
    int t   = threadIdx.x;

    // load 2 points, pack into 1 chain: lane-half h holds point h
    f2 pp2, nx2, ny2, nz2;
    #pragma unroll
    for (int h = 0; h < 2; ++h) {
        int pid = g * PPG_K + h * TKNN + t;
        float p0 = pts[3 * pid], p1 = pts[3 * pid + 1], p2 = pts[3 * pid + 2];
        float pp = __fadd_rn(__fadd_rn(__fmul_rn(p0, p0), __fmul_rn(p1, p1)),
                             __fmul_rn(p2, p2));
        pp2[h] = pp;
        nx2[h] = __fmul_rn(-2.0f, p0);   // exact
        ny2[h] = __fmul_rn(-2.0f, p1);
        nz2[h] = __fmul_rn(-2.0f, p2);
    }

    const float4* np = n4 + c * CHN;
    // divergence-taint: vzero is 0 in a VGPR the compiler cannot prove uniform,
    // forcing vector (global_load_dwordx4) codegen for the batch loads.
    int vzero;
    asm volatile("v_mov_b32 %0, 0" : "=v"(vzero));
    const float4* npv = np + vzero;

    float bestA[PPT], bestB[PPT];
    int   qbA[PPT],   qbB[PPT];
    #pragma unroll
    for (int p = 0; p < PPT; ++p) {
        bestA[p] = 3.4e38f; bestB[p] = 3.4e38f; qbA[p] = 0; qbB[p] = 0;
    }

    float4 A0[4], B0[4], A1[4], B1[4];       // VGPR double buffers (64 VGPRs)
    loadb(npv, 0, A0, B0);                   // prologue: batch 0 in flight

    #pragma unroll 1
    for (int jj = 0; jj < HALF; jj += 8) {
        loadb(npv, jj + 4, A1, B1);          // issue batch k+1
        step4(A0, B0, jj, nx2, ny2, nz2, pp2, bestA, qbA, bestB, qbB);
        int nj = (jj + 8 < HALF) ? jj + 8 : 0;   // clamp: last prefetch is dead
        loadb(npv, nj, A0, B0);              // issue batch k+2
        step4(A1, B1, jj + 4, nx2, ny2, nz2, pp2, bestA, qbA, bestB, qbB);
    }

    // endgame: merge halves (tie -> A = smaller node indices), recover exact
    // node index within the winning quad, plain store of this chunk's partial
    #pragma unroll
    for (int p = 0; p < PPT; ++p) {
        float bA = bestA[p], bB = bestB[p];
        float b  = fminf(bA, bB);                 // exact IEEE min
        int base = (bB < bA) ? (HALF + qbB[p]) : qbA[p];

        float nx = nx2[p], ny = ny2[p], nz = nz2[p], pp = pp2[p];
        float dd[4];
        #pragma unroll
        for (int o = 0; o < 4; ++o) {
            float4 v = np[base + o];         // per-lane addr, L2-hot (32 KB table)
            float m = __fmul_rn(nx, v.x);
            float r = __builtin_fmaf(ny, v.y, m);
            r       = __builtin_fmaf(nz, v.z, r);
            dd[o]   = __fadd_rn(__fadd_rn(pp, r), v.w);   // bit-identical to pk path
        }
        int off = 3;                          // descending chain -> first match wins
        if (dd[2] == b) off = 2;
        if (dd[1] == b) off = 1;
        if (dd[0] == b) off = 0;

        int pid = g * PPG_K + p * TKNN + t;
        u64 key = ((u64)f2ord(b) << 32) | (uint)(c * CHN + base + off);
        part[(size_t)c * NPTS + pid] = key;   // one writer per slot, coalesced
    }
}

// --- K2: 8-way u64 min-reduce partials, decode, write d2/id/pcd, histogram ---
// [proven R4/R7]
__global__ __launch_bounds__(256) void merge_hist(const u64* __restrict__ part,
                                                  float* __restrict__ out_d2,
                                                  float* __restrict__ out_id,
                                                  int* __restrict__ pcd,
                                                  u16* __restrict__ hist16,
                                                  float* __restrict__ patch) {
    __shared__ uint lh[NNODES];
    int g = blockIdx.x, t = threadIdx.x;
    patch[(size_t)g * 256 + t] = 0.0f;       // 256x256 = full 65536-float patch zeroed
    for (int i = t; i < NNODES; i += 256) lh[i] = 0;
    __syncthreads();

    #pragma unroll
    for (int q = 0; q < GSZ / 256; ++q) {
        int pid = g * GSZ + q * 256 + t;
        u64 key = part[pid];                 // chunk 0
        #pragma unroll
        for (int cc = 1; cc < NCHUNK; ++cc) {
            u64 k2 = part[(size_t)cc * NPTS + pid];   // coalesced per plane
            key = (k2 < key) ? k2 : key;     // min key == (min d2, then min node)
        }
        uint bi = (uint)key;                 // low 32: node index
        float d = ord2f((uint)(key >> 32));  // exact d2 decode
        atomicAdd(&lh[bi], 1u);
        out_d2[pid] = d;
        out_id[pid] = (float)bi;             // exact: bi < 2^24
        pcd[pid]    = (int)bi;
    }
    __syncthreads();
    for (int i = t; i < NNODES; i += 256)
        hist16[(size_t)g * NNODES + i] = (u16)lh[i];   // contiguous stores
}

// --- K3: per-node exclusive prefix across the 256 groups; offs in [node][group] ---
__global__ __launch_bounds__(256) void scan_offs(const u16* __restrict__ hist16,
                                                 uint* __restrict__ offs) {
    int t = threadIdx.x, lane = t & 63, wv = t >> 6;
    int node = blockIdx.x * 4 + wv;

    uint v0 = hist16[(size_t)(4 * lane + 0) * NNODES + node];
    uint v1 = hist16[(size_t)(4 * lane + 1) * NNODES + node];
    uint v2 = hist16[(size_t)(4 * lane + 2) * NNODES + node];
    uint v3 = hist16[(size_t)(4 * lane + 3) * NNODES + node];
    uint s = v0 + v1 + v2 + v3;
    uint a = s;
    #pragma unroll
    for (int d = 1; d < 64; d <<= 1) {
        uint y = __shfl_up(a, d, 64);
        if (lane >= d) a += y;
    }
    uint base = a - s;                        // exclusive across lanes
    uint4 o = make_uint4(base, base + v0, base + v0 + v1, base + v0 + v1 + v2);
    *(uint4*)(offs + (size_t)node * NG + 4 * lane) = o;   // contiguous 16B store
}

// --- K4: stable scatter of first-32 point indices per node ---
__global__ __launch_bounds__(256) void scatter_patch(const int* __restrict__ pcd,
                                                     const uint* __restrict__ offs,
                                                     float* __restrict__ patch) {
    __shared__ int ids[GSZ];
    int g = blockIdx.x, t = threadIdx.x;
    ids[t]       = pcd[g * GSZ + t];
    ids[256 + t] = pcd[g * GSZ + 256 + t];
    __syncthreads();

    int i0 = t, i1 = 256 + t;
    int my0 = ids[i0], my1 = ids[i1];
    int r0 = 0, r1 = 0;
    #pragma unroll 8
    for (int j = 0; j < GSZ; ++j) {
        int id = ids[j];                      // broadcast LDS read, conflict-free
        r0 += (j < i0 && id == my0) ? 1 : 0;
        r1 += (j < i1 && id == my1) ? 1 : 0;
    }
    uint rk0 = offs[(size_t)my0 * NG + g] + (uint)r0;
    uint rk1 = offs[(size_t)my1 * NG + g] + (uint)r1;
    if (rk0 < KSEL) patch[(size_t)my0 * KSEL + rk0] = (float)(g * GSZ + i0);
    if (rk1 < KSEL) patch[(size_t)my1 * KSEL + rk1] = (float)(g * GSZ + i1);
}

extern "C" void kernel_launch(void* const* d_in, const int* in_sizes, int n_in,
                              void* d_out, int out_size, void* d_ws, size_t ws_size,
                              hipStream_t stream) {
    const float* pts   = (const float*)d_in[0];
    const float* nodes = (const float*)d_in[1];

    float* out       = (float*)d_out;
    float* out_d2    = out;                  // 131072 floats
    float* out_id    = out + NPTS;           // 131072 floats
    float* out_patch = out + 2 * NPTS;       // 65536 floats

    // workspace: ~11.6 MB (layout proven R4/R7)
    char* ws = (char*)d_ws;
    u64*   part   = (u64*) ws;                               // 8 MB  (8 x 131072 u64)
    u16*   hist16 = (u16*) (ws + (8 << 20));                 // 1 MB  (256 x 2048 u16)
    uint*  offs   = (uint*) (ws + (9 << 20));                // 2 MB  (2048 x 256 u32)
    int*   pcd    = (int*)  (ws + (11 << 20));               // 512 KB
    float4* n4    = (float4*)(ws + (11 << 20) + (512 << 10));// 32 KB

    prep_nodes<<<NNODES / 256, 256, 0, stream>>>(nodes, n4);
    knn_part<<<NGRP_K * NCHUNK, TKNN, 0, stream>>>(pts, n4, part);
    merge_hist<<<NG, 256, 0, stream>>>(part, out_d2, out_id, pcd, hist16, out_patch);
    scan_offs<<<NNODES / 4, 256, 0, stream>>>(hist16, offs);
    scatter_patch<<<NG, 256, 0, stream>>>(pcd, offs, out_patch);
}

// Round 9
// 122.257 us; speedup vs baseline: 1.2345x; 1.2345x over previous
//
#include <hip/hip_runtime.h>
#include <hip/hip_bf16.h>

#define NPTS   131072
#define NNODES 2048
#define KSEL   32

// ---- knn decomposition ----
#define TKNN   256                 // threads per knn block
#define PPT    2                   // points per thread = 1 packed f32x2 chain
#define PPG_K  (TKNN * PPT)        // 512 points per knn group
#define NGRP_K (NPTS / PPG_K)      // 256 knn groups
#define NCHUNK 8                   // node chunks; partial-array merge (no atomics)
#define CHN    (NNODES / NCHUNK)   // 256 nodes per chunk
#define HALF   (CHN / 2)           // 128: dual-accumulator split point
// grid = 256*8 = 2048 blocks

// ---- grouping/scatter decomposition ----
#define GSZ    512                 // points per stability group
#define NG     (NPTS / GSZ)        // 256 groups

typedef unsigned int uint;
typedef unsigned short u16;
typedef unsigned long long u64;
typedef float f2 __attribute__((ext_vector_type(2)));

__device__ __forceinline__ f2 splat(float s) { return (f2){s, s}; }

// order-preserving fp32 -> u32 (handles tiny-negative cancellation results)
__device__ __forceinline__ uint f2ord(float d) {
    uint b = __float_as_uint(d);
    return (b & 0x80000000u) ? ~b : (b | 0x80000000u);
}
__device__ __forceinline__ float ord2f(uint t) {
    uint b = (t & 0x80000000u) ? (t ^ 0x80000000u) : ~t;
    return __uint_as_float(b);
}

// --- K0: pack nodes {x,y,z,|n|^2} (8 blocks) --- [proven R1/R7]
__global__ __launch_bounds__(256) void prep_nodes(const float* __restrict__ nodes,
                                                  float4* __restrict__ n4) {
    int i = blockIdx.x * 256 + threadIdx.x;
    float x = nodes[3 * i], y = nodes[3 * i + 1], z = nodes[3 * i + 2];
    // |n|^2 with numpy's mul-then-add rounding
    float nn = __fadd_rn(__fadd_rn(__fmul_rn(x, x), __fmul_rn(y, y)), __fmul_rn(z, z));
    n4[i] = make_float4(x, y, z, nn);
}

// --- K1: partial 1-NN, 2 pts/thread as 1 packed-f32 chain (v_pk_* VOP3P) ---
// [argmin logic + s_load operand path proven R7; store path proven R4/R7]
// NEW vs R7: explicit SGPR rotation across the backedge. Batch k+1's two
// s_load_dwordx16 are issued BEFORE batch k's ~192cy of compute, so the
// ~200cy scalar-load latency is hidden; the lgkmcnt wait lands at the
// bottom-of-loop copy instead of before the compute. Arithmetic byte-identical
// to R7 (same pinned-rounding distance sequence, dual-half quad-deferred
// argmin, strict-improvement base, endgame exact recompute, tie -> half A).
__global__ __launch_bounds__(256) void knn_part(const float* __restrict__ pts,
                                                const float4* __restrict__ n4,
                                                u64* __restrict__ part) {
    int bid = blockIdx.x;
    int c   = bid & (NCHUNK - 1);            // block-uniform chunk
    int g   = bid >> 3;                      // knn point group
    int t   = threadIdx.x;

    // load 2 points, pack into 1 chain: lane-half h holds point h
    f2 pp2, nx2, ny2, nz2;
    #pragma unroll
    for (int h = 0; h < 2; ++h) {
        int pid = g * PPG_K + h * TKNN + t;
        float p0 = pts[3 * pid], p1 = pts[3 * pid + 1], p2 = pts[3 * pid + 2];
        float pp = __fadd_rn(__fadd_rn(__fmul_rn(p0, p0), __fmul_rn(p1, p1)),
                             __fmul_rn(p2, p2));
        pp2[h] = pp;
        nx2[h] = __fmul_rn(-2.0f, p0);   // exact
        ny2[h] = __fmul_rn(-2.0f, p1);
        nz2[h] = __fmul_rn(-2.0f, p2);
    }

    const float4* np = n4 + c * CHN;         // block-uniform base -> scalar s_load
    float bestA[PPT], bestB[PPT];
    int   qbA[PPT],   qbB[PPT];
    #pragma unroll
    for (int p = 0; p < PPT; ++p) {
        bestA[p] = 3.4e38f; bestB[p] = 3.4e38f; qbA[p] = 0; qbB[p] = 0;
    }

    // prologue: current batch (nodes [0,4) and [HALF, HALF+4)) in SGPRs
    float4 cA0 = np[0],        cA1 = np[1],        cA2 = np[2],        cA3 = np[3];
    float4 cB0 = np[HALF],     cB1 = np[HALF + 1], cB2 = np[HALF + 2], cB3 = np[HALF + 3];

    #pragma unroll 1
    for (int jj = 0; jj < HALF; jj += 4) {
        // issue batch k+1's scalar loads first (last iter: dead reload of 0)
        int nj = (jj + 4) & (HALF - 1);
        float4 nA0 = np[nj + 0],        nA1 = np[nj + 1];
        float4 nA2 = np[nj + 2],        nA3 = np[nj + 3];
        float4 nB0 = np[HALF + nj + 0], nB1 = np[HALF + nj + 1];
        float4 nB2 = np[HALF + nj + 2], nB3 = np[HALF + nj + 3];

        // compute on current batch (no dependency on the loads above)
        f2 dA0, dA1, dA2, dA3, dB0, dB1, dB2, dB3;
        {   f2 m = nx2 * splat(cA0.x);
            f2 r = __builtin_elementwise_fma(ny2, splat(cA0.y), m);
            r    = __builtin_elementwise_fma(nz2, splat(cA0.z), r);
            dA0  = (pp2 + r) + splat(cA0.w); }
        {   f2 m = nx2 * splat(cA1.x);
            f2 r = __builtin_elementwise_fma(ny2, splat(cA1.y), m);
            r    = __builtin_elementwise_fma(nz2, splat(cA1.z), r);
            dA1  = (pp2 + r) + splat(cA1.w); }
        {   f2 m = nx2 * splat(cA2.x);
            f2 r = __builtin_elementwise_fma(ny2, splat(cA2.y), m);
            r    = __builtin_elementwise_fma(nz2, splat(cA2.z), r);
            dA2  = (pp2 + r) + splat(cA2.w); }
        {   f2 m = nx2 * splat(cA3.x);
            f2 r = __builtin_elementwise_fma(ny2, splat(cA3.y), m);
            r    = __builtin_elementwise_fma(nz2, splat(cA3.z), r);
            dA3  = (pp2 + r) + splat(cA3.w); }
        {   f2 m = nx2 * splat(cB0.x);
            f2 r = __builtin_elementwise_fma(ny2, splat(cB0.y), m);
            r    = __builtin_elementwise_fma(nz2, splat(cB0.z), r);
            dB0  = (pp2 + r) + splat(cB0.w); }
        {   f2 m = nx2 * splat(cB1.x);
            f2 r = __builtin_elementwise_fma(ny2, splat(cB1.y), m);
            r    = __builtin_elementwise_fma(nz2, splat(cB1.z), r);
            dB1  = (pp2 + r) + splat(cB1.w); }
        {   f2 m = nx2 * splat(cB2.x);
            f2 r = __builtin_elementwise_fma(ny2, splat(cB2.y), m);
            r    = __builtin_elementwise_fma(nz2, splat(cB2.z), r);
            dB2  = (pp2 + r) + splat(cB2.w); }
        {   f2 m = nx2 * splat(cB3.x);
            f2 r = __builtin_elementwise_fma(ny2, splat(cB3.y), m);
            r    = __builtin_elementwise_fma(nz2, splat(cB3.z), r);
            dB3  = (pp2 + r) + splat(cB3.w); }

        #pragma unroll
        for (int p = 0; p < PPT; ++p) {
            float eA0 = p ? dA0.y : dA0.x;
            float eA1 = p ? dA1.y : dA1.x;
            float eA2 = p ? dA2.y : dA2.x;
            float eA3 = p ? dA3.y : dA3.x;
            float mA  = fminf(fminf(bestA[p], eA0), eA1);   // v_min3_f32
            float nA  = fminf(fminf(mA, eA2), eA3);         // v_min3_f32
            qbA[p]    = (nA < bestA[p]) ? jj : qbA[p];      // strict: first quad wins
            bestA[p]  = nA;

            float eB0 = p ? dB0.y : dB0.x;
            float eB1 = p ? dB1.y : dB1.x;
            float eB2 = p ? dB2.y : dB2.x;
            float eB3 = p ? dB3.y : dB3.x;
            float mB  = fminf(fminf(bestB[p], eB0), eB1);
            float nB  = fminf(fminf(mB, eB2), eB3);
            qbB[p]    = (nB < bestB[p]) ? jj : qbB[p];      // relative to HALF
            bestB[p]  = nB;
        }

        // rotate: the lgkmcnt wait for batch k+1 lands HERE, after compute
        cA0 = nA0; cA1 = nA1; cA2 = nA2; cA3 = nA3;
        cB0 = nB0; cB1 = nB1; cB2 = nB2; cB3 = nB3;
    }

    // endgame: merge halves (tie -> A = smaller node indices), recover exact
    // node index within the winning quad, plain store of this chunk's partial
    #pragma unroll
    for (int p = 0; p < PPT; ++p) {
        float bA = bestA[p], bB = bestB[p];
        float b  = fminf(bA, bB);                 // exact IEEE min
        int base = (bB < bA) ? (HALF + qbB[p]) : qbA[p];

        float nx = nx2[p], ny = ny2[p], nz = nz2[p], pp = pp2[p];
        float dd[4];
        #pragma unroll
        for (int o = 0; o < 4; ++o) {
            float4 v = np[base + o];         // per-lane addr, L2-hot (32 KB table)
            float m = __fmul_rn(nx, v.x);
            float r = __builtin_fmaf(ny, v.y, m);
            r       = __builtin_fmaf(nz, v.z, r);
            dd[o]   = __fadd_rn(__fadd_rn(pp, r), v.w);   // bit-identical to pk path
        }
        int off = 3;                          // descending chain -> first match wins
        if (dd[2] == b) off = 2;
        if (dd[1] == b) off = 1;
        if (dd[0] == b) off = 0;

        int pid = g * PPG_K + p * TKNN + t;
        u64 key = ((u64)f2ord(b) << 32) | (uint)(c * CHN + base + off);
        part[(size_t)c * NPTS + pid] = key;   // one writer per slot, coalesced
    }
}

// --- K2: 8-way u64 min-reduce partials, decode, write d2/id/pcd, histogram ---
// [proven R4/R7]
__global__ __launch_bounds__(256) void merge_hist(const u64* __restrict__ part,
                                                  float* __restrict__ out_d2,
                                                  float* __restrict__ out_id,
                                                  int* __restrict__ pcd,
                                                  u16* __restrict__ hist16,
                                                  float* __restrict__ patch) {
    __shared__ uint lh[NNODES];
    int g = blockIdx.x, t = threadIdx.x;
    patch[(size_t)g * 256 + t] = 0.0f;       // 256x256 = full 65536-float patch zeroed
    for (int i = t; i < NNODES; i += 256) lh[i] = 0;
    __syncthreads();

    #pragma unroll
    for (int q = 0; q < GSZ / 256; ++q) {
        int pid = g * GSZ + q * 256 + t;
        u64 key = part[pid];                 // chunk 0
        #pragma unroll
        for (int cc = 1; cc < NCHUNK; ++cc) {
            u64 k2 = part[(size_t)cc * NPTS + pid];   // coalesced per plane
            key = (k2 < key) ? k2 : key;     // min key == (min d2, then min node)
        }
        uint bi = (uint)key;                 // low 32: node index
        float d = ord2f((uint)(key >> 32));  // exact d2 decode
        atomicAdd(&lh[bi], 1u);
        out_d2[pid] = d;
        out_id[pid] = (float)bi;             // exact: bi < 2^24
        pcd[pid]    = (int)bi;
    }
    __syncthreads();
    for (int i = t; i < NNODES; i += 256)
        hist16[(size_t)g * NNODES + i] = (u16)lh[i];   // contiguous stores
}

// --- K3: per-node exclusive prefix across the 256 groups; offs in [node][group] ---
__global__ __launch_bounds__(256) void scan_offs(const u16* __restrict__ hist16,
                                                 uint* __restrict__ offs) {
    int t = threadIdx.x, lane = t & 63, wv = t >> 6;
    int node = blockIdx.x * 4 + wv;

    uint v0 = hist16[(size_t)(4 * lane + 0) * NNODES + node];
    uint v1 = hist16[(size_t)(4 * lane + 1) * NNODES + node];
    uint v2 = hist16[(size_t)(4 * lane + 2) * NNODES + node];
    uint v3 = hist16[(size_t)(4 * lane + 3) * NNODES + node];
    uint s = v0 + v1 + v2 + v3;
    uint a = s;
    #pragma unroll
    for (int d = 1; d < 64; d <<= 1) {
        uint y = __shfl_up(a, d, 64);
        if (lane >= d) a += y;
    }
    uint base = a - s;                        // exclusive across lanes
    uint4 o = make_uint4(base, base + v0, base + v0 + v1, base + v0 + v1 + v2);
    *(uint4*)(offs + (size_t)node * NG + 4 * lane) = o;   // contiguous 16B store
}

// --- K4: stable scatter of first-32 point indices per node ---
__global__ __launch_bounds__(256) void scatter_patch(const int* __restrict__ pcd,
                                                     const uint* __restrict__ offs,
                                                     float* __restrict__ patch) {
    __shared__ int ids[GSZ];
    int g = blockIdx.x, t = threadIdx.x;
    ids[t]       = pcd[g * GSZ + t];
    ids[256 + t] = pcd[g * GSZ + 256 + t];
    __syncthreads();

    int i0 = t, i1 = 256 + t;
    int my0 = ids[i0], my1 = ids[i1];
    int r0 = 0, r1 = 0;
    #pragma unroll 8
    for (int j = 0; j < GSZ; ++j) {
        int id = ids[j];                      // broadcast LDS read, conflict-free
        r0 += (j < i0 && id == my0) ? 1 : 0;
        r1 += (j < i1 && id == my1) ? 1 : 0;
    }
    uint rk0 = offs[(size_t)my0 * NG + g] + (uint)r0;
    uint rk1 = offs[(size_t)my1 * NG + g] + (uint)r1;
    if (rk0 < KSEL) patch[(size_t)my0 * KSEL + rk0] = (float)(g * GSZ + i0);
    if (rk1 < KSEL) patch[(size_t)my1 * KSEL + rk1] = (float)(g * GSZ + i1);
}

extern "C" void kernel_launch(void* const* d_in, const int* in_sizes, int n_in,
                              void* d_out, int out_size, void* d_ws, size_t ws_size,
                              hipStream_t stream) {
    const float* pts   = (const float*)d_in[0];
    const float* nodes = (const float*)d_in[1];

    float* out       = (float*)d_out;
    float* out_d2    = out;                  // 131072 floats
    float* out_id    = out + NPTS;           // 131072 floats
    float* out_patch = out + 2 * NPTS;       // 65536 floats

    // workspace: ~11.6 MB (layout proven R4/R7)
    char* ws = (char*)d_ws;
    u64*   part   = (u64*) ws;                               // 8 MB  (8 x 131072 u64)
    u16*   hist16 = (u16*) (ws + (8 << 20));                 // 1 MB  (256 x 2048 u16)
    uint*  offs   = (uint*) (ws + (9 << 20));                // 2 MB  (2048 x 256 u32)
    int*   pcd    = (int*)  (ws + (11 << 20));               // 512 KB
    float4* n4    = (float4*)(ws + (11 << 20) + (512 << 10));// 32 KB

    prep_nodes<<<NNODES / 256, 256, 0, stream>>>(nodes, n4);
    knn_part<<<NGRP_K * NCHUNK, TKNN, 0, stream>>>(pts, n4, part);
    merge_hist<<<NG, 256, 0, stream>>>(part, out_d2, out_id, pcd, hist16, out_patch);
    scan_offs<<<NNODES / 4, 256, 0, stream>>>(hist16, offs);
    scatter_patch<<<NG, 256, 0, stream>>>(pcd, offs, out_patch);
}

// Round 10
// 121.211 us; speedup vs baseline: 1.2452x; 1.0086x over previous
//
#include <hip/hip_runtime.h>
#include <hip/hip_bf16.h>

#define NPTS   131072
#define NNODES 2048
#define KSEL   32

// ---- knn decomposition ----
#define TKNN   256                 // threads per knn block
#define PPT    4                   // points per thread = 2 packed f32x2 chains
#define PPG_K  (TKNN * PPT)        // 1024 points per knn group
#define NGRP_K (NPTS / PPG_K)      // 128 knn groups
#define NCHUNK 8                   // node chunks; partial-array merge (no atomics)
#define CHN    (NNODES / NCHUNK)   // 256 nodes per chunk
#define HALF   (CHN / 2)           // 128: dual-accumulator split point
// grid = 128*8 = 1024 blocks = 4 blocks/CU = 4 waves/SIMD; per-iter compute
// (~380cy) covers the ~200cy scalar-load latency (convoy-stall fix via ratio,
// not via compiler-defeated source pipelining).

// ---- grouping/scatter decomposition ----
#define GSZ    512                 // points per stability group
#define NG     (NPTS / GSZ)        // 256 groups

typedef unsigned int uint;
typedef unsigned short u16;
typedef unsigned long long u64;
typedef float f2 __attribute__((ext_vector_type(2)));

__device__ __forceinline__ f2 splat(float s) { return (f2){s, s}; }

// order-preserving fp32 -> u32 (handles tiny-negative cancellation results)
__device__ __forceinline__ uint f2ord(float d) {
    uint b = __float_as_uint(d);
    return (b & 0x80000000u) ? ~b : (b | 0x80000000u);
}
__device__ __forceinline__ float ord2f(uint t) {
    uint b = (t & 0x80000000u) ? (t ^ 0x80000000u) : ~t;
    return __uint_as_float(b);
}

// exact distance sequence (pinned rounding): m=nx*x; r=fma(ny,y,m);
// r=fma(nz,z,r); d=(pp+r)+nn  -- lane-wise IEEE f32, bit-identical to the
// accepted reference-matching sequence.
__device__ __forceinline__ f2 dist2(const f2& nx2, const f2& ny2, const f2& nz2,
                                    const f2& pp2, float4 v) {
    f2 m = nx2 * splat(v.x);                               // v_pk_mul_f32
    f2 r = __builtin_elementwise_fma(ny2, splat(v.y), m);  // v_pk_fma_f32
    r    = __builtin_elementwise_fma(nz2, splat(v.z), r);  // v_pk_fma_f32
    return (pp2 + r) + splat(v.w);                         // 2x v_pk_add_f32
}

// --- K0: pack nodes {x,y,z,|n|^2} (8 blocks) --- [proven R1/R7]
__global__ __launch_bounds__(256) void prep_nodes(const float* __restrict__ nodes,
                                                  float4* __restrict__ n4) {
    int i = blockIdx.x * 256 + threadIdx.x;
    float x = nodes[3 * i], y = nodes[3 * i + 1], z = nodes[3 * i + 2];
    // |n|^2 with numpy's mul-then-add rounding
    float nn = __fadd_rn(__fadd_rn(__fmul_rn(x, x), __fmul_rn(y, y)), __fmul_rn(z, z));
    n4[i] = make_float4(x, y, z, nn);
}

// --- K1: partial 1-NN, 4 pts/thread as 2 packed-f32 chains (v_pk_* VOP3P) ---
// [PPT=4 chain layout proven R0/R1; dual-half quad argmin proven R3/R7;
//  s_load operand path proven R7; store path proven R4/R7]
// Node operands via block-uniform global reads -> s_load into SGPRs.
// Dual-half quad-deferred argmin: 8 independent min3 chains/thread; strict
// improvement keeps first occurrence; tie across halves -> A (lower indices);
// endgame recomputes the winning quad bit-identically, first exact match.
// Plain coalesced store into part[c*NPTS+pid] (no atomics, no init).
__global__ __launch_bounds__(256) void knn_part(const float* __restrict__ pts,
                                                const float4* __restrict__ n4,
                                                u64* __restrict__ part) {
    int bid = blockIdx.x;
    int c   = bid & (NCHUNK - 1);            // block-uniform chunk
    int g   = bid >> 3;                      // knn point group
    int t   = threadIdx.x;

    // load 4 points, pack into 2 chains: chain q holds points (2q, 2q+1)
    f2 pp2[2], nx2[2], ny2[2], nz2[2];
    #pragma unroll
    for (int q = 0; q < 2; ++q) {
        #pragma unroll
        for (int h = 0; h < 2; ++h) {
            int pid = g * PPG_K + (2 * q + h) * TKNN + t;
            float p0 = pts[3 * pid], p1 = pts[3 * pid + 1], p2 = pts[3 * pid + 2];
            float pp = __fadd_rn(__fadd_rn(__fmul_rn(p0, p0), __fmul_rn(p1, p1)),
                                 __fmul_rn(p2, p2));
            pp2[q][h] = pp;
            nx2[q][h] = __fmul_rn(-2.0f, p0);   // exact
            ny2[q][h] = __fmul_rn(-2.0f, p1);
            nz2[q][h] = __fmul_rn(-2.0f, p2);
        }
    }

    const float4* np = n4 + c * CHN;         // block-uniform base -> scalar s_load
    float bestA[PPT], bestB[PPT];
    int   qbA[PPT],   qbB[PPT];
    #pragma unroll
    for (int p = 0; p < PPT; ++p) {
        bestA[p] = 3.4e38f; bestB[p] = 3.4e38f; qbA[p] = 0; qbB[p] = 0;
    }

    #pragma unroll 2
    for (int jj = 0; jj < HALF; jj += 4) {
        float4 a0 = np[jj + 0];              // uniform addr -> s_load_dwordx16
        float4 a1 = np[jj + 1];
        float4 a2 = np[jj + 2];
        float4 a3 = np[jj + 3];
        float4 b0 = np[HALF + jj + 0];
        float4 b1 = np[HALF + jj + 1];
        float4 b2 = np[HALF + jj + 2];
        float4 b3 = np[HALF + jj + 3];

        f2 dA[2][4], dB[2][4];               // static indices only (unrolled)
        #pragma unroll
        for (int q = 0; q < 2; ++q) {
            dA[q][0] = dist2(nx2[q], ny2[q], nz2[q], pp2[q], a0);
            dA[q][1] = dist2(nx2[q], ny2[q], nz2[q], pp2[q], a1);
            dA[q][2] = dist2(nx2[q], ny2[q], nz2[q], pp2[q], a2);
            dA[q][3] = dist2(nx2[q], ny2[q], nz2[q], pp2[q], a3);
            dB[q][0] = dist2(nx2[q], ny2[q], nz2[q], pp2[q], b0);
            dB[q][1] = dist2(nx2[q], ny2[q], nz2[q], pp2[q], b1);
            dB[q][2] = dist2(nx2[q], ny2[q], nz2[q], pp2[q], b2);
            dB[q][3] = dist2(nx2[q], ny2[q], nz2[q], pp2[q], b3);
        }

        #pragma unroll
        for (int p = 0; p < PPT; ++p) {
            int q = p >> 1;
            float eA0 = (p & 1) ? dA[q][0].y : dA[q][0].x;
            float eA1 = (p & 1) ? dA[q][1].y : dA[q][1].x;
            float eA2 = (p & 1) ? dA[q][2].y : dA[q][2].x;
            float eA3 = (p & 1) ? dA[q][3].y : dA[q][3].x;
            float mA  = fminf(fminf(bestA[p], eA0), eA1);   // v_min3_f32
            float nA  = fminf(fminf(mA, eA2), eA3);         // v_min3_f32
            qbA[p]    = (nA < bestA[p]) ? jj : qbA[p];      // strict: first quad wins
            bestA[p]  = nA;

            float eB0 = (p & 1) ? dB[q][0].y : dB[q][0].x;
            float eB1 = (p & 1) ? dB[q][1].y : dB[q][1].x;
            float eB2 = (p & 1) ? dB[q][2].y : dB[q][2].x;
            float eB3 = (p & 1) ? dB[q][3].y : dB[q][3].x;
            float mB  = fminf(fminf(bestB[p], eB0), eB1);
            float nB  = fminf(fminf(mB, eB2), eB3);
            qbB[p]    = (nB < bestB[p]) ? jj : qbB[p];      // relative to HALF
            bestB[p]  = nB;
        }
    }

    // endgame: merge halves (tie -> A = smaller node indices), recover exact
    // node index within the winning quad, plain store of this chunk's partial
    #pragma unroll
    for (int p = 0; p < PPT; ++p) {
        float bA = bestA[p], bB = bestB[p];
        float b  = fminf(bA, bB);                 // exact IEEE min
        int base = (bB < bA) ? (HALF + qbB[p]) : qbA[p];

        int q = p >> 1, h = p & 1;
        float nx = nx2[q][h], ny = ny2[q][h], nz = nz2[q][h], pp = pp2[q][h];
        float dd[4];
        #pragma unroll
        for (int o = 0; o < 4; ++o) {
            float4 v = np[base + o];         // per-lane addr, L2-hot (32 KB table)
            float m = __fmul_rn(nx, v.x);
            float r = __builtin_fmaf(ny, v.y, m);
            r       = __builtin_fmaf(nz, v.z, r);
            dd[o]   = __fadd_rn(__fadd_rn(pp, r), v.w);   // bit-identical to pk path
        }
        int off = 3;                          // descending chain -> first match wins
        if (dd[2] == b) off = 2;
        if (dd[1] == b) off = 1;
        if (dd[0] == b) off = 0;

        int pid = g * PPG_K + p * TKNN + t;
        u64 key = ((u64)f2ord(b) << 32) | (uint)(c * CHN + base + off);
        part[(size_t)c * NPTS + pid] = key;   // one writer per slot, coalesced
    }
}

// --- K2: 8-way u64 min-reduce partials, decode, write d2/id/pcd, histogram ---
// [proven R4/R7]
__global__ __launch_bounds__(256) void merge_hist(const u64* __restrict__ part,
                                                  float* __restrict__ out_d2,
                                                  float* __restrict__ out_id,
                                                  int* __restrict__ pcd,
                                                  u16* __restrict__ hist16,
                                                  float* __restrict__ patch) {
    __shared__ uint lh[NNODES];
    int g = blockIdx.x, t = threadIdx.x;
    patch[(size_t)g * 256 + t] = 0.0f;       // 256x256 = full 65536-float patch zeroed
    for (int i = t; i < NNODES; i += 256) lh[i] = 0;
    __syncthreads();

    #pragma unroll
    for (int q = 0; q < GSZ / 256; ++q) {
        int pid = g * GSZ + q * 256 + t;
        u64 key = part[pid];                 // chunk 0
        #pragma unroll
        for (int cc = 1; cc < NCHUNK; ++cc) {
            u64 k2 = part[(size_t)cc * NPTS + pid];   // coalesced per plane
            key = (k2 < key) ? k2 : key;     // min key == (min d2, then min node)
        }
        uint bi = (uint)key;                 // low 32: node index
        float d = ord2f((uint)(key >> 32));  // exact d2 decode
        atomicAdd(&lh[bi], 1u);
        out_d2[pid] = d;
        out_id[pid] = (float)bi;             // exact: bi < 2^24
        pcd[pid]    = (int)bi;
    }
    __syncthreads();
    for (int i = t; i < NNODES; i += 256)
        hist16[(size_t)g * NNODES + i] = (u16)lh[i];   // contiguous stores
}

// --- K3: per-node exclusive prefix across the 256 groups; offs in [node][group] ---
__global__ __launch_bounds__(256) void scan_offs(const u16* __restrict__ hist16,
                                                 uint* __restrict__ offs) {
    int t = threadIdx.x, lane = t & 63, wv = t >> 6;
    int node = blockIdx.x * 4 + wv;

    uint v0 = hist16[(size_t)(4 * lane + 0) * NNODES + node];
    uint v1 = hist16[(size_t)(4 * lane + 1) * NNODES + node];
    uint v2 = hist16[(size_t)(4 * lane + 2) * NNODES + node];
    uint v3 = hist16[(size_t)(4 * lane + 3) * NNODES + node];
    uint s = v0 + v1 + v2 + v3;
    uint a = s;
    #pragma unroll
    for (int d = 1; d < 64; d <<= 1) {
        uint y = __shfl_up(a, d, 64);
        if (lane >= d) a += y;
    }
    uint base = a - s;                        // exclusive across lanes
    uint4 o = make_uint4(base, base + v0, base + v0 + v1, base + v0 + v1 + v2);
    *(uint4*)(offs + (size_t)node * NG + 4 * lane) = o;   // contiguous 16B store
}

// --- K4: stable scatter of first-32 point indices per node ---
__global__ __launch_bounds__(256) void scatter_patch(const int* __restrict__ pcd,
                                                     const uint* __restrict__ offs,
                                                     float* __restrict__ patch) {
    __shared__ int ids[GSZ];
    int g = blockIdx.x, t = threadIdx.x;
    ids[t]       = pcd[g * GSZ + t];
    ids[256 + t] = pcd[g * GSZ + 256 + t];
    __syncthreads();

    int i0 = t, i1 = 256 + t;
    int my0 = ids[i0], my1 = ids[i1];
    int r0 = 0, r1 = 0;
    #pragma unroll 8
    for (int j = 0; j < GSZ; ++j) {
        int id = ids[j];                      // broadcast LDS read, conflict-free
        r0 += (j < i0 && id == my0) ? 1 : 0;
        r1 += (j < i1 && id == my1) ? 1 : 0;
    }
    uint rk0 = offs[(size_t)my0 * NG + g] + (uint)r0;
    uint rk1 = offs[(size_t)my1 * NG + g] + (uint)r1;
    if (rk0 < KSEL) patch[(size_t)my0 * KSEL + rk0] = (float)(g * GSZ + i0);
    if (rk1 < KSEL) patch[(size_t)my1 * KSEL + rk1] = (float)(g * GSZ + i1);
}

extern "C" void kernel_launch(void* const* d_in, const int* in_sizes, int n_in,
                              void* d_out, int out_size, void* d_ws, size_t ws_size,
                              hipStream_t stream) {
    const float* pts   = (const float*)d_in[0];
    const float* nodes = (const float*)d_in[1];

    float* out       = (float*)d_out;
    float* out_d2    = out;                  // 131072 floats
    float* out_id    = out + NPTS;           // 131072 floats
    float* out_patch = out + 2 * NPTS;       // 65536 floats

    // workspace: ~11.6 MB (layout proven R4/R7)
    char* ws = (char*)d_ws;
    u64*   part   = (u64*) ws;                               // 8 MB  (8 x 131072 u64)
    u16*   hist16 = (u16*) (ws + (8 << 20));                 // 1 MB  (256 x 2048 u16)
    uint*  offs   = (uint*) (ws + (9 << 20));                // 2 MB  (2048 x 256 u32)
    int*   pcd    = (int*)  (ws + (11 << 20));               // 512 KB
    float4* n4    = (float4*)(ws + (11 << 20) + (512 << 10));// 32 KB

    prep_nodes<<<NNODES / 256, 256, 0, stream>>>(nodes, n4);
    knn_part<<<NGRP_K * NCHUNK, TKNN, 0, stream>>>(pts, n4, part);
    merge_hist<<<NG, 256, 0, stream>>>(part, out_d2, out_id, pcd, hist16, out_patch);
    scan_offs<<<NNODES / 4, 256, 0, stream>>>(hist16, offs);
    scatter_patch<<<NG, 256, 0, stream>>>(pcd, offs, out_patch);
}

// Round 11
// 119.734 us; speedup vs baseline: 1.2605x; 1.0123x over previous
//
#include <hip/hip_runtime.h>
#include <hip/hip_bf16.h>

#define NPTS   131072
#define NNODES 2048
#define KSEL   32

// ---- knn decomposition ----
#define TKNN   256                 // threads per knn block
#define PPT    4                   // points per thread = 2 packed f32x2 chains
#define PPG_K  (TKNN * PPT)        // 1024 points per knn group
#define NGRP_K (NPTS / PPG_K)      // 128 knn groups
#define NCHUNK 8                   // node chunks; partial-array merge (no atomics)
#define CHN    (NNODES / NCHUNK)   // 256 nodes per chunk
#define HALF   (CHN / 2)           // 128: dual-accumulator split point
// grid = 128*8 = 1024 blocks = 4 blocks/CU = 4 waves/SIMD

// ---- grouping/scatter decomposition ----
#define GSZ    512                 // points per stability group
#define NG     (NPTS / GSZ)        // 256 groups

typedef unsigned int uint;
typedef unsigned short u16;
typedef unsigned long long u64;
typedef float f2  __attribute__((ext_vector_type(2)));
typedef float sf16 __attribute__((ext_vector_type(16)));

__device__ __forceinline__ f2 splat(float s) { return (f2){s, s}; }

// order-preserving fp32 -> u32 (handles tiny-negative cancellation results)
__device__ __forceinline__ uint f2ord(float d) {
    uint b = __float_as_uint(d);
    return (b & 0x80000000u) ? ~b : (b | 0x80000000u);
}
__device__ __forceinline__ float ord2f(uint t) {
    uint b = (t & 0x80000000u) ? (t ^ 0x80000000u) : ~t;
    return __uint_as_float(b);
}

// exact distance sequence (pinned rounding): m=nx*x; r=fma(ny,y,m);
// r=fma(nz,z,r); d=(pp+r)+nn -- lane-wise IEEE f32, bit-identical to the
// accepted reference-matching sequence (operand register class is irrelevant
// to the arithmetic).
__device__ __forceinline__ f2 dist2c(const f2& nx2, const f2& ny2, const f2& nz2,
                                     const f2& pp2,
                                     float x, float y, float z, float w) {
    f2 m = nx2 * splat(x);                                 // v_pk_mul_f32
    f2 r = __builtin_elementwise_fma(ny2, splat(y), m);    // v_pk_fma_f32
    r    = __builtin_elementwise_fma(nz2, splat(z), r);    // v_pk_fma_f32
    return (pp2 + r) + splat(w);                           // 2x v_pk_add_f32
}

// un-sinkable 64B scalar load: volatile asm cannot be moved by the scheduler,
// so the issue point (before compute) and the wait point (after compute) are
// pinned -- this is the fix for hipcc sinking s_loads to their first use,
// which serialized ~8 x 250cy K$-miss waits per iteration (R7/R9/R10 all
// invariant at ~3100cy/iter; VALU issue is only ~1520cy/iter/SIMD).
__device__ __forceinline__ sf16 sload16(const float4* p) {
    sf16 r;
    asm volatile("s_load_dwordx16 %0, %1, 0x0" : "=&s"(r) : "s"(p));
    return r;
}
// wait for all outstanding scalar loads; sched_barrier keeps hipcc from
// hoisting register-only uses above the wait (guide rule #18).
__device__ __forceinline__ void swait() {
    asm volatile("s_waitcnt lgkmcnt(0)" ::: "memory");
    __builtin_amdgcn_sched_barrier(0);
}

// --- K0: pack nodes {x,y,z,|n|^2} (8 blocks) --- [proven R1/R7]
__global__ __launch_bounds__(256) void prep_nodes(const float* __restrict__ nodes,
                                                  float4* __restrict__ n4) {
    int i = blockIdx.x * 256 + threadIdx.x;
    float x = nodes[3 * i], y = nodes[3 * i + 1], z = nodes[3 * i + 2];
    // |n|^2 with numpy's mul-then-add rounding
    float nn = __fadd_rn(__fadd_rn(__fmul_rn(x, x), __fmul_rn(y, y)), __fmul_rn(z, z));
    n4[i] = make_float4(x, y, z, nn);
}

// --- K1: partial 1-NN, 4 pts/thread as 2 packed-f32 chains (v_pk_* VOP3P) ---
// [argmin logic proven R3/R7/R10; store path proven R4/R7; NEW: asm-pipelined
//  scalar operand delivery -- 2-deep ping-pong of s_load_dwordx16 buffers]
// One buffer = A-quad (4 nodes at base jb) + B-quad (4 nodes at HALF+jb).
// Schedule per iteration: wait(buf0); issue(buf1); compute(buf0);
//                         wait(buf1); issue(buf0.next); compute(buf1).
// Dual-half quad-deferred argmin: strict improvement keeps first occurrence;
// tie across halves -> A (lower indices); endgame recomputes the winning quad
// bit-identically and takes the first exact match. Plain coalesced store into
// part[c*NPTS+pid] (no atomics, no init).
__global__ __launch_bounds__(256) void knn_part(const float* __restrict__ pts,
                                                const float4* __restrict__ n4,
                                                u64* __restrict__ part) {
    int bid = blockIdx.x;
    int c   = bid & (NCHUNK - 1);            // block-uniform chunk
    int g   = bid >> 3;                      // knn point group
    int t   = threadIdx.x;

    // load 4 points, pack into 2 chains: chain q holds points (2q, 2q+1)
    f2 pp2[2], nx2[2], ny2[2], nz2[2];
    #pragma unroll
    for (int q = 0; q < 2; ++q) {
        #pragma unroll
        for (int h = 0; h < 2; ++h) {
            int pid = g * PPG_K + (2 * q + h) * TKNN + t;
            float p0 = pts[3 * pid], p1 = pts[3 * pid + 1], p2 = pts[3 * pid + 2];
            float pp = __fadd_rn(__fadd_rn(__fmul_rn(p0, p0), __fmul_rn(p1, p1)),
                                 __fmul_rn(p2, p2));
            pp2[q][h] = pp;
            nx2[q][h] = __fmul_rn(-2.0f, p0);   // exact
            ny2[q][h] = __fmul_rn(-2.0f, p1);
            nz2[q][h] = __fmul_rn(-2.0f, p2);
        }
    }

    const float4* np = n4 + c * CHN;         // block-uniform base (SGPR pair)
    float bestA[PPT], bestB[PPT];
    int   qbA[PPT],   qbB[PPT];
    #pragma unroll
    for (int p = 0; p < PPT; ++p) {
        bestA[p] = 3.4e38f; bestB[p] = 3.4e38f; qbA[p] = 0; qbB[p] = 0;
    }

    // one buffer-step: distances + argmin update for A-quad@jb, B-quad@HALF+jb
    auto stepbuf = [&](const sf16& A, const sf16& B, int jb) {
        f2 dA[2][4], dB[2][4];               // static indices only (unrolled)
        #pragma unroll
        for (int q = 0; q < 2; ++q) {
            #pragma unroll
            for (int k = 0; k < 4; ++k) {
                dA[q][k] = dist2c(nx2[q], ny2[q], nz2[q], pp2[q],
                                  A[4 * k], A[4 * k + 1], A[4 * k + 2], A[4 * k + 3]);
                dB[q][k] = dist2c(nx2[q], ny2[q], nz2[q], pp2[q],
                                  B[4 * k], B[4 * k + 1], B[4 * k + 2], B[4 * k + 3]);
            }
        }
        #pragma unroll
        for (int p = 0; p < PPT; ++p) {
            int q = p >> 1;
            float eA0 = (p & 1) ? dA[q][0].y : dA[q][0].x;
            float eA1 = (p & 1) ? dA[q][1].y : dA[q][1].x;
            float eA2 = (p & 1) ? dA[q][2].y : dA[q][2].x;
            float eA3 = (p & 1) ? dA[q][3].y : dA[q][3].x;
            float mA  = fminf(fminf(bestA[p], eA0), eA1);   // v_min3_f32
            float nA  = fminf(fminf(mA, eA2), eA3);         // v_min3_f32
            qbA[p]    = (nA < bestA[p]) ? jb : qbA[p];      // strict: first quad wins
            bestA[p]  = nA;

            float eB0 = (p & 1) ? dB[q][0].y : dB[q][0].x;
            float eB1 = (p & 1) ? dB[q][1].y : dB[q][1].x;
            float eB2 = (p & 1) ? dB[q][2].y : dB[q][2].x;
            float eB3 = (p & 1) ? dB[q][3].y : dB[q][3].x;
            float mB  = fminf(fminf(bestB[p], eB0), eB1);
            float nB  = fminf(fminf(mB, eB2), eB3);
            qbB[p]    = (nB < bestB[p]) ? jb : qbB[p];      // relative to HALF
            bestB[p]  = nB;
        }
    };

    sf16 A0, B0, A1, B1;                     // 64 SGPRs of staging
    A0 = sload16(np);                        // prologue: buffer 0 @ jb=0
    B0 = sload16(np + HALF);

    #pragma unroll 1
    for (int jj = 0; jj < HALF; jj += 8) {
        swait();                             // buf0 data ready
        A1 = sload16(np + (jj + 4));         // issue buf1 (in flight over compute)
        B1 = sload16(np + (HALF + jj + 4));
        stepbuf(A0, B0, jj);

        swait();                             // buf1 data ready
        int nj = (jj + 8 < HALF) ? (jj + 8) : 0;   // last prefetch is dead
        A0 = sload16(np + nj);               // issue buf0 for next iteration
        B0 = sload16(np + (HALF + nj));
        stepbuf(A1, B1, jj + 4);
    }

    // endgame: merge halves (tie -> A = smaller node indices), recover exact
    // node index within the winning quad, plain store of this chunk's partial
    #pragma unroll
    for (int p = 0; p < PPT; ++p) {
        float bA = bestA[p], bB = bestB[p];
        float b  = fminf(bA, bB);                 // exact IEEE min
        int base = (bB < bA) ? (HALF + qbB[p]) : qbA[p];

        int q = p >> 1, h = p & 1;
        float nx = nx2[q][h], ny = ny2[q][h], nz = nz2[q][h], pp = pp2[q][h];
        float dd[4];
        #pragma unroll
        for (int o = 0; o < 4; ++o) {
            float4 v = np[base + o];         // per-lane addr, L2-hot (32 KB table)
            float m = __fmul_rn(nx, v.x);
            float r = __builtin_fmaf(ny, v.y, m);
            r       = __builtin_fmaf(nz, v.z, r);
            dd[o]   = __fadd_rn(__fadd_rn(pp, r), v.w);   // bit-identical to pk path
        }
        int off = 3;                          // descending chain -> first match wins
        if (dd[2] == b) off = 2;
        if (dd[1] == b) off = 1;
        if (dd[0] == b) off = 0;

        int pid = g * PPG_K + p * TKNN + t;
        u64 key = ((u64)f2ord(b) << 32) | (uint)(c * CHN + base + off);
        part[(size_t)c * NPTS + pid] = key;   // one writer per slot, coalesced
    }
}

// --- K2: 8-way u64 min-reduce partials, decode, write d2/id/pcd, histogram ---
// [proven R4/R7]
__global__ __launch_bounds__(256) void merge_hist(const u64* __restrict__ part,
                                                  float* __restrict__ out_d2,
                                                  float* __restrict__ out_id,
                                                  int* __restrict__ pcd,
                                                  u16* __restrict__ hist16,
                                                  float* __restrict__ patch) {
    __shared__ uint lh[NNODES];
    int g = blockIdx.x, t = threadIdx.x;
    patch[(size_t)g * 256 + t] = 0.0f;       // 256x256 = full 65536-float patch zeroed
    for (int i = t; i < NNODES; i += 256) lh[i] = 0;
    __syncthreads();

    #pragma unroll
    for (int q = 0; q < GSZ / 256; ++q) {
        int pid = g * GSZ + q * 256 + t;
        u64 key = part[pid];                 // chunk 0
        #pragma unroll
        for (int cc = 1; cc < NCHUNK; ++cc) {
            u64 k2 = part[(size_t)cc * NPTS + pid];   // coalesced per plane
            key = (k2 < key) ? k2 : key;     // min key == (min d2, then min node)
        }
        uint bi = (uint)key;                 // low 32: node index
        float d = ord2f((uint)(key >> 32));  // exact d2 decode
        atomicAdd(&lh[bi], 1u);
        out_d2[pid] = d;
        out_id[pid] = (float)bi;             // exact: bi < 2^24
        pcd[pid]    = (int)bi;
    }
    __syncthreads();
    for (int i = t; i < NNODES; i += 256)
        hist16[(size_t)g * NNODES + i] = (u16)lh[i];   // contiguous stores
}

// --- K3: per-node exclusive prefix across the 256 groups; offs in [node][group] ---
__global__ __launch_bounds__(256) void scan_offs(const u16* __restrict__ hist16,
                                                 uint* __restrict__ offs) {
    int t = threadIdx.x, lane = t & 63, wv = t >> 6;
    int node = blockIdx.x * 4 + wv;

    uint v0 = hist16[(size_t)(4 * lane + 0) * NNODES + node];
    uint v1 = hist16[(size_t)(4 * lane + 1) * NNODES + node];
    uint v2 = hist16[(size_t)(4 * lane + 2) * NNODES + node];
    uint v3 = hist16[(size_t)(4 * lane + 3) * NNODES + node];
    uint s = v0 + v1 + v2 + v3;
    uint a = s;
    #pragma unroll
    for (int d = 1; d < 64; d <<= 1) {
        uint y = __shfl_up(a, d, 64);
        if (lane >= d) a += y;
    }
    uint base = a - s;                        // exclusive across lanes
    uint4 o = make_uint4(base, base + v0, base + v0 + v1, base + v0 + v1 + v2);
    *(uint4*)(offs + (size_t)node * NG + 4 * lane) = o;   // contiguous 16B store
}

// --- K4: stable scatter of first-32 point indices per node ---
__global__ __launch_bounds__(256) void scatter_patch(const int* __restrict__ pcd,
                                                     const uint* __restrict__ offs,
                                                     float* __restrict__ patch) {
    __shared__ int ids[GSZ];
    int g = blockIdx.x, t = threadIdx.x;
    ids[t]       = pcd[g * GSZ + t];
    ids[256 + t] = pcd[g * GSZ + 256 + t];
    __syncthreads();

    int i0 = t, i1 = 256 + t;
    int my0 = ids[i0], my1 = ids[i1];
    int r0 = 0, r1 = 0;
    #pragma unroll 8
    for (int j = 0; j < GSZ; ++j) {
        int id = ids[j];                      // broadcast LDS read, conflict-free
        r0 += (j < i0 && id == my0) ? 1 : 0;
        r1 += (j < i1 && id == my1) ? 1 : 0;
    }
    uint rk0 = offs[(size_t)my0 * NG + g] + (uint)r0;
    uint rk1 = offs[(size_t)my1 * NG + g] + (uint)r1;
    if (rk0 < KSEL) patch[(size_t)my0 * KSEL + rk0] = (float)(g * GSZ + i0);
    if (rk1 < KSEL) patch[(size_t)my1 * KSEL + rk1] = (float)(g * GSZ + i1);
}

extern "C" void kernel_launch(void* const* d_in, const int* in_sizes, int n_in,
                              void* d_out, int out_size, void* d_ws, size_t ws_size,
                              hipStream_t stream) {
    const float* pts   = (const float*)d_in[0];
    const float* nodes = (const float*)d_in[1];

    float* out       = (float*)d_out;
    float* out_d2    = out;                  // 131072 floats
    float* out_id    = out + NPTS;           // 131072 floats
    float* out_patch = out + 2 * NPTS;       // 65536 floats

    // workspace: ~11.6 MB (layout proven R4/R7)
    char* ws = (char*)d_ws;
    u64*   part   = (u64*) ws;                               // 8 MB  (8 x 131072 u64)
    u16*   hist16 = (u16*) (ws + (8 << 20));                 // 1 MB  (256 x 2048 u16)
    uint*  offs   = (uint*) (ws + (9 << 20));                // 2 MB  (2048 x 256 u32)
    int*   pcd    = (int*)  (ws + (11 << 20));               // 512 KB
    float4* n4    = (float4*)(ws + (11 << 20) + (512 << 10));// 32 KB

    prep_nodes<<<NNODES / 256, 256, 0, stream>>>(nodes, n4);
    knn_part<<<NGRP_K * NCHUNK, TKNN, 0, stream>>>(pts, n4, part);
    merge_hist<<<NG, 256, 0, stream>>>(part, out_d2, out_id, pcd, hist16, out_patch);
    scan_offs<<<NNODES / 4, 256, 0, stream>>>(hist16, offs);
    scatter_patch<<<NG, 256, 0, stream>>>(pcd, offs, out_patch);
}